// Round 4
// baseline (151.693 us; speedup 1.0000x reference)
//
#include <hip/hip_runtime.h>
#include <hip/hip_bf16.h>

#define B_ 32
#define D_ 64
#define N_ 254
#define L_ 16
#define H_ 128
#define P_ 96
#define PAIRS (B_*D_)    // 2048
#define XPAIR (N_*L_)    // 4064 floats per (b,d) pair
#define OUT0  (B_*P_*D_) // 196608 floats (output 0)

// ws layout (floats):
#define WS_M    128      // M[256] = W_enc W_enc^T
#define WS_VK   384      // vK[16] = W_enc @ K
#define WS_BW   400      // bW[16] = W_enc @ b_enc
#define WS_BK   416      // bK     = b_enc . K
#define WS_G    432      // G[254*16] = pos @ W_enc^T
#define WS_PK   4496     // pK[254]   = pos @ K
#define WS_KP   4752     // Kpart[16*128]

// ---- stage 1: partial column sums of pos (254 x 128), coalesced ----
__global__ __launch_bounds__(256) void preK(const float* __restrict__ pos,
                                            float* __restrict__ ws) {
    __shared__ float red[256];
    int t = threadIdx.x;
    int h = t & 127, j = t >> 7;
    int n0 = blockIdx.x * 16;
    float acc = 0.f;
    #pragma unroll
    for (int r = 0; r < 8; r++) {
        int n = n0 + j + 2 * r;
        if (n < N_) acc += pos[n * H_ + h];
    }
    red[t] = acc;
    __syncthreads();
    if (t < 128) ws[WS_KP + blockIdx.x * 128 + t] = red[t] + red[t + 128];
}

// ---- stage 2: G,pK (blocks 0..253) + M,vK,bW,bK (block 254) ----
__global__ __launch_bounds__(128) void pre2b(const float* __restrict__ W_enc,
                                             const float* __restrict__ b_enc,
                                             const float* __restrict__ pos,
                                             float* __restrict__ ws) {
    __shared__ float Ks[128], bL[128], pLDS[128], red[128], red2[128];
    __shared__ float WL[2048];
    int t = threadIdx.x;
    int n = blockIdx.x;

    {
        float b = b_enc[t];
        float s = 254.f * b;
        #pragma unroll
        for (int g = 0; g < 16; g++) s += ws[WS_KP + g * 128 + t];
        Ks[t] = s;
        bL[t] = b;
    }

    if (n < N_) {
        pLDS[t] = pos[n * H_ + t];
        __syncthreads();
        {
            int l = t >> 3, c = t & 7;
            const float* w = W_enc + l * H_ + c * 16;
            const float* p = pLDS + c * 16;
            float s = 0.f;
            #pragma unroll
            for (int i = 0; i < 16; i++) s += p[i] * w[i];
            red[t] = s;
            red2[t] = pLDS[t] * Ks[t];
        }
        __syncthreads();
        if (t < 16) {
            float s = 0.f;
            #pragma unroll
            for (int c = 0; c < 8; c++) s += red[t * 8 + c];
            ws[WS_G + n * 16 + t] = s;
        }
        if (t >= 64) {
            int lane = t - 64;
            float s = red2[lane] + red2[lane + 64];
            for (int off = 32; off; off >>= 1) s += __shfl_down(s, off);
            if (lane == 0) ws[WS_PK + n] = s;
        }
    } else {
        for (int i = t; i < 512; i += 128) {
            float4 v = ((const float4*)W_enc)[i];
            float* p = &WL[i * 4];
            p[0] = v.x; p[1] = v.y; p[2] = v.z; p[3] = v.w;
        }
        __syncthreads();
        #pragma unroll
        for (int e0 = 0; e0 < 2; e0++) {
            int e = e0 * 128 + t;
            int l1 = e >> 4, l2 = e & 15;
            float s = 0.f;
            for (int h = 0; h < H_; h++) s += WL[l1 * H_ + h] * WL[l2 * H_ + h];
            ws[WS_M + e] = s;
        }
        if (t < 16) {
            float s1 = 0.f, s2 = 0.f;
            for (int h = 0; h < H_; h++) {
                float w = WL[t * H_ + h];
                s1 += w * Ks[h];
                s2 += w * bL[h];
            }
            ws[WS_VK + t] = s1;
            ws[WS_BW + t] = s2;
        }
        if (t == 16) {
            float s = 0.f;
            for (int h = 0; h < H_; h++) s += bL[h] * Ks[h];
            ws[WS_BK] = s;
        }
    }
}

// ---- main: one wave per (b,d) pair, x in registers, 1 barrier ----
__global__ __launch_bounds__(256) void mainker(const float* __restrict__ x,
                                               const float* __restrict__ W1,
                                               const float* __restrict__ b1,
                                               const float* __restrict__ W2,
                                               const float* __restrict__ b2,
                                               const float* __restrict__ ws,
                                               float* __restrict__ out) {
    __shared__ float Wsm[304];       // M[256], vK@256, bW@272, bK@288
    __shared__ float Gp[N_ * 20];    // G rows padded to 20 (bank spread, 16B-aligned)
    __shared__ float pKs[N_];
    __shared__ float vSh[4][16];
    __shared__ float hSh[4][128];

    int t = threadIdx.x;
    int wv = t >> 6, lane = t & 63;
    int bd = blockIdx.x * 4 + wv;    // 512 blocks x 4 waves = 2048

    const float* xp = x + (size_t)bd * XPAIR;
    float*       cp = out + OUT0 + (size_t)bd * XPAIR;

    // ---- x rows into registers (16 independent dwordx4 per lane-set) ----
    float4 xr[4][4];
    #pragma unroll
    for (int r = 0; r < 4; r++) {
        int n = lane + 64 * r;
        if (n < N_) {
            const float4* row = (const float4*)(xp + n * 16);
            #pragma unroll
            for (int j = 0; j < 4; j++) xr[r][j] = row[j];
        } else {
            #pragma unroll
            for (int j = 0; j < 4; j++) xr[r][j] = make_float4(0.f, 0.f, 0.f, 0.f);
        }
    }
    // ---- mirror copy x -> out1 ----
    #pragma unroll
    for (int r = 0; r < 4; r++) {
        int n = lane + 64 * r;
        if (n < N_) {
            float4* row = (float4*)(cp + n * 16);
            #pragma unroll
            for (int j = 0; j < 4; j++) row[j] = xr[r][j];
        }
    }

    // ---- stage ws tables into LDS (shared by 4 waves) ----
    for (int i = t; i < 304; i += 256) Wsm[i] = ws[WS_M + i];
    for (int i = t; i < N_;  i += 256) pKs[i] = ws[WS_PK + i];
    for (int i = t; i < 1016; i += 256) {
        float4 g = ((const float4*)(ws + WS_G))[i];
        int idx = i * 4, n = idx >> 4, l = idx & 15;
        *(float4*)&Gp[n * 20 + l] = g;
    }
    __syncthreads();   // the only block barrier

    // ---- xs[l] = sum_n x[n,l] : lane-local + 6-level butterfly ----
    float xs[16];
    #pragma unroll
    for (int k = 0; k < 4; k++) {
        float4 a = xr[0][k], b = xr[1][k], c = xr[2][k], d = xr[3][k];
        xs[4*k+0] = a.x + b.x + c.x + d.x;
        xs[4*k+1] = a.y + b.y + c.y + d.y;
        xs[4*k+2] = a.z + b.z + c.z + d.z;
        xs[4*k+3] = a.w + b.w + c.w + d.w;
    }
    #pragma unroll
    for (int off = 32; off; off >>= 1) {
        #pragma unroll
        for (int l = 0; l < 16; l++) xs[l] += __shfl_xor(xs[l], off);
    }

    // ---- v = vK + M^T xs : lanes 0..15 compute, broadcast via LDS ----
    if (lane < 16) {
        float acc = Wsm[256 + lane];
        #pragma unroll
        for (int l2 = 0; l2 < 16; l2++) acc += xs[l2] * Wsm[l2 * 16 + lane];
        vSh[wv][lane] = acc;
    }
    __builtin_amdgcn_wave_barrier();
    float v[16];
    #pragma unroll
    for (int k = 0; k < 4; k++) *(float4*)&v[4*k] = *(const float4*)&vSh[wv][4*k];

    // ---- s0 = bK + xs.bW (uniform LDS reads) ----
    float s0 = Wsm[288];
    #pragma unroll
    for (int l = 0; l < 16; l++) s0 += xs[l] * Wsm[272 + l];

    // ---- score per row ----
    float sc[4];
    #pragma unroll
    for (int r = 0; r < 4; r++) {
        int n = lane + 64 * r;
        if (n < N_) {
            float acc = s0 + pKs[n];
            const float* g = &Gp[n * 20];
            #pragma unroll
            for (int k = 0; k < 4; k++) {
                float4 gv = *(const float4*)&g[4*k];
                float4 xv = xr[r][k];
                acc += xv.x * v[4*k+0] + xv.y * v[4*k+1] + xv.z * v[4*k+2] + xv.w * v[4*k+3];
                acc += gv.x * xs[4*k+0] + gv.y * xs[4*k+1] + gv.z * xs[4*k+2] + gv.w * xs[4*k+3];
            }
            sc[r] = acc;
        } else sc[r] = 0.f;
    }

    // ---- denom = sum |score| : butterfly ----
    float den = fabsf(sc[0]) + fabsf(sc[1]) + fabsf(sc[2]) + fabsf(sc[3]);
    #pragma unroll
    for (int off = 32; off; off >>= 1) den += __shfl_xor(den, off);
    float inv = 1.0f / den;

    // ---- pooled[l] = inv * sum_n x[n,l]*score[n] ----
    float pl[16];
    #pragma unroll
    for (int k = 0; k < 4; k++) {
        float4 a = xr[0][k], b = xr[1][k], c = xr[2][k], d = xr[3][k];
        pl[4*k+0] = a.x*sc[0] + b.x*sc[1] + c.x*sc[2] + d.x*sc[3];
        pl[4*k+1] = a.y*sc[0] + b.y*sc[1] + c.y*sc[2] + d.y*sc[3];
        pl[4*k+2] = a.z*sc[0] + b.z*sc[1] + c.z*sc[2] + d.z*sc[3];
        pl[4*k+3] = a.w*sc[0] + b.w*sc[1] + c.w*sc[2] + d.w*sc[3];
    }
    #pragma unroll
    for (int off = 32; off; off >>= 1) {
        #pragma unroll
        for (int l = 0; l < 16; l++) pl[l] += __shfl_xor(pl[l], off);
    }
    #pragma unroll
    for (int l = 0; l < 16; l++) pl[l] *= inv;

    // ---- h = leaky_relu(pooled @ W1 + b1): lane owns j=lane, lane+64 ----
    {
        float a0 = b1[lane], a1 = b1[lane + 64];
        #pragma unroll
        for (int l = 0; l < 16; l++) {
            a0 += pl[l] * W1[l * H_ + lane];
            a1 += pl[l] * W1[l * H_ + lane + 64];
        }
        hSh[wv][lane]      = a0 > 0.f ? a0 : 0.2f * a0;
        hSh[wv][lane + 64] = a1 > 0.f ? a1 : 0.2f * a1;
    }
    __builtin_amdgcn_wave_barrier();

    // ---- out0[b,p,d] = h @ W2 + b2 : p = lane (+64 for lane<32) ----
    {
        int b = bd >> 6, d = bd & 63;
        float* outp = out + b * (P_ * D_) + d;
        float acc0 = b2[lane];
        float acc1 = (lane < 32) ? b2[lane + 64] : 0.f;
        const float* hw = &hSh[wv][0];
        #pragma unroll 8
        for (int j = 0; j < 128; j++) {
            float hj = hw[j];
            acc0 += hj * W2[j * P_ + lane];
            if (lane < 32) acc1 += hj * W2[j * P_ + lane + 64];
        }
        outp[lane * D_] = acc0;
        if (lane < 32) outp[(lane + 64) * D_] = acc1;
    }
}

extern "C" void kernel_launch(void* const* d_in, const int* in_sizes, int n_in,
                              void* d_out, int out_size, void* d_ws, size_t ws_size,
                              hipStream_t stream) {
    const float* x     = (const float*)d_in[0];
    const float* W_enc = (const float*)d_in[1];
    const float* b_enc = (const float*)d_in[2];
    const float* W1    = (const float*)d_in[3];
    const float* b1    = (const float*)d_in[4];
    const float* W2    = (const float*)d_in[5];
    const float* b2    = (const float*)d_in[6];
    const float* pos   = (const float*)d_in[7];
    float* ws  = (float*)d_ws;
    float* out = (float*)d_out;

    hipLaunchKernelGGL(preK,    dim3(16),  dim3(256), 0, stream, pos, ws);
    hipLaunchKernelGGL(pre2b,   dim3(255), dim3(128), 0, stream, W_enc, b_enc, pos, ws);
    hipLaunchKernelGGL(mainker, dim3(512), dim3(256), 0, stream, x, W1, b1, W2, b2, ws, out);
}

// Round 6
// 132.351 us; speedup vs baseline: 1.1461x; 1.1461x over previous
//
#include <hip/hip_runtime.h>
#include <hip/hip_bf16.h>

#define B_ 32
#define D_ 64
#define N_ 254
#define L_ 16
#define H_ 128
#define P_ 96
#define PAIRS (B_*D_)    // 2048
#define XPAIR (N_*L_)    // 4064 floats per (b,d) pair
#define OUT0  (B_*P_*D_) // 196608 floats (output 0)

typedef float float4n __attribute__((ext_vector_type(4)));

// ws layout (floats):
#define WS_M    128      // M[256] = W_enc W_enc^T
#define WS_VK   384      // vK[16] = W_enc @ K
#define WS_BW   400      // bW[16] = W_enc @ b_enc
#define WS_BK   416      // bK     = b_enc . K
#define WS_G    432      // G[254*16] = pos @ W_enc^T
#define WS_PK   4496     // pK[254]   = pos @ K
#define WS_KP   4752     // Kpart[16*128]
#define WS_PL   8192     // pooled[2048][16]

// ---- stage 1: partial column sums of pos ----
__global__ __launch_bounds__(256) void preK(const float* __restrict__ pos,
                                            float* __restrict__ ws) {
    __shared__ float red[256];
    int t = threadIdx.x;
    int h = t & 127, j = t >> 7;
    int n0 = blockIdx.x * 16;
    float acc = 0.f;
    #pragma unroll
    for (int r = 0; r < 8; r++) {
        int n = n0 + j + 2 * r;
        if (n < N_) acc += pos[n * H_ + h];
    }
    red[t] = acc;
    __syncthreads();
    if (t < 128) ws[WS_KP + blockIdx.x * 128 + t] = red[t] + red[t + 128];
}

// ---- stage 2: G,pK (blocks 0..253) + M,vK,bW,bK (block 254) ----
__global__ __launch_bounds__(128) void pre2b(const float* __restrict__ W_enc,
                                             const float* __restrict__ b_enc,
                                             const float* __restrict__ pos,
                                             float* __restrict__ ws) {
    __shared__ float Ks[128], bL[128], pLDS[128], red[128], red2[128];
    __shared__ float WL[2048];
    int t = threadIdx.x;
    int n = blockIdx.x;

    {
        float b = b_enc[t];
        float s = 254.f * b;
        #pragma unroll
        for (int g = 0; g < 16; g++) s += ws[WS_KP + g * 128 + t];
        Ks[t] = s;
        bL[t] = b;
    }

    if (n < N_) {
        pLDS[t] = pos[n * H_ + t];
        __syncthreads();
        {
            int l = t >> 3, c = t & 7;
            const float* w = W_enc + l * H_ + c * 16;
            const float* p = pLDS + c * 16;
            float s = 0.f;
            #pragma unroll
            for (int i = 0; i < 16; i++) s += p[i] * w[i];
            red[t] = s;
            red2[t] = pLDS[t] * Ks[t];
        }
        __syncthreads();
        if (t < 16) {
            float s = 0.f;
            #pragma unroll
            for (int c = 0; c < 8; c++) s += red[t * 8 + c];
            ws[WS_G + n * 16 + t] = s;
        }
        if (t >= 64) {
            int lane = t - 64;
            float s = red2[lane] + red2[lane + 64];
            for (int off = 32; off; off >>= 1) s += __shfl_down(s, off);
            if (lane == 0) ws[WS_PK + n] = s;
        }
    } else {
        for (int i = t; i < 512; i += 128) {
            float4 v = ((const float4*)W_enc)[i];
            float* p = &WL[i * 4];
            p[0] = v.x; p[1] = v.y; p[2] = v.z; p[3] = v.w;
        }
        __syncthreads();
        #pragma unroll
        for (int e0 = 0; e0 < 2; e0++) {
            int e = e0 * 128 + t;
            int l1 = e >> 4, l2 = e & 15;
            float s = 0.f;
            for (int h = 0; h < H_; h++) s += WL[l1 * H_ + h] * WL[l2 * H_ + h];
            ws[WS_M + e] = s;
        }
        if (t < 16) {
            float s1 = 0.f, s2 = 0.f;
            for (int h = 0; h < H_; h++) {
                float w = WL[t * H_ + h];
                s1 += w * Ks[h];
                s2 += w * bL[h];
            }
            ws[WS_VK + t] = s1;
            ws[WS_BW + t] = s2;
        }
        if (t == 16) {
            float s = 0.f;
            for (int h = 0; h < H_; h++) s += bL[h] * Ks[h];
            ws[WS_BK] = s;
        }
    }
}

// ---- main pass: block per bd; copy + score + pool; minimal line traffic ----
__global__ __launch_bounds__(256) void mainker2(const float* __restrict__ x,
                                                float* __restrict__ ws,
                                                float* __restrict__ out) {
    __shared__ float xf[N_ * 17];   // 4318 floats, stride-17 padded
    __shared__ float red[256];
    __shared__ float scoreS[N_];
    __shared__ float xsS[16], vS[16];
    __shared__ float s0S, denomS;

    int t  = threadIdx.x;
    int bd = blockIdx.x;

    // ---- coalesced load x -> LDS, mirror copy -> out1 (only HBM traffic) ----
    const float4n* xv = (const float4n*)(x + (size_t)bd * XPAIR);
    float4n*       cv = (float4n*)(out + OUT0) + (size_t)bd * (XPAIR / 4);
    for (int i = t; i < XPAIR / 4; i += 256) {
        float4n v = xv[i];
        __builtin_nontemporal_store(v, cv + i);
        int idx = i * 4, n = idx >> 4, l = idx & 15;   // l in {0,4,8,12}
        float* p = &xf[n * 17 + l];
        p[0] = v.x; p[1] = v.y; p[2] = v.z; p[3] = v.w;
    }
    __syncthreads();

    // ---- xs[l] = sum_n x[n,l] ----
    {
        int l = t & 15, g = t >> 4;
        float s = 0.f;
        for (int n = g; n < N_; n += 16) s += xf[n * 17 + l];
        red[t] = s;
    }
    __syncthreads();
    if (t < 16) {
        float s = 0.f;
        for (int g = 0; g < 16; g++) s += red[g * 16 + t];
        xsS[t] = s;
    }
    __syncthreads();

    // ---- v = vK + M^T xs; s0 = bK + xs.bW  (tables are L1-hot) ----
    if (t < 16) {
        float s = ws[WS_VK + t];
        for (int l2 = 0; l2 < 16; l2++) s += xsS[l2] * ws[WS_M + l2 * 16 + t];
        vS[t] = s;
    } else if (t == 16) {
        float s = ws[WS_BK];
        for (int l = 0; l < 16; l++) s += xsS[l] * ws[WS_BW + l];
        s0S = s;
    }
    __syncthreads();

    // ---- score[n] = s0 + pK[n] + x[n].v + xs.G[n]  (G read direct, L1-hot) ----
    if (t < N_) {
        const float4* Gn = (const float4*)(ws + WS_G + t * 16);
        float4 g0 = Gn[0], g1 = Gn[1], g2 = Gn[2], g3 = Gn[3];
        const float* xr = &xf[t * 17];
        float s = s0S + ws[WS_PK + t];
        s += xr[0]*vS[0] + xr[1]*vS[1] + xr[2]*vS[2] + xr[3]*vS[3]
           + xr[4]*vS[4] + xr[5]*vS[5] + xr[6]*vS[6] + xr[7]*vS[7]
           + xr[8]*vS[8] + xr[9]*vS[9] + xr[10]*vS[10] + xr[11]*vS[11]
           + xr[12]*vS[12] + xr[13]*vS[13] + xr[14]*vS[14] + xr[15]*vS[15];
        s += g0.x*xsS[0] + g0.y*xsS[1] + g0.z*xsS[2] + g0.w*xsS[3]
           + g1.x*xsS[4] + g1.y*xsS[5] + g1.z*xsS[6] + g1.w*xsS[7]
           + g2.x*xsS[8] + g2.y*xsS[9] + g2.z*xsS[10] + g2.w*xsS[11]
           + g3.x*xsS[12] + g3.y*xsS[13] + g3.z*xsS[14] + g3.w*xsS[15];
        scoreS[t] = s;
    }
    __syncthreads();

    // ---- denom = sum |score| ----
    if (t < 64) {
        float s = 0.f;
        for (int n = t; n < N_; n += 64) s += fabsf(scoreS[n]);
        for (int off = 32; off; off >>= 1) s += __shfl_down(s, off);
        if (t == 0) denomS = s;
    }
    __syncthreads();

    // ---- pooled[l] = (sum_n x[n,l]*score[n]) / denom  -> ws ----
    {
        int l = t & 15, g = t >> 4;
        float s = 0.f;
        for (int n = g; n < N_; n += 16) s += xf[n * 17 + l] * scoreS[n];
        red[t] = s;
    }
    __syncthreads();
    if (t < 16) {
        float s = 0.f;
        for (int g = 0; g < 16; g++) s += red[g * 16 + t];
        ws[WS_PL + bd * 16 + t] = s / denomS;
    }
}

// ---- FFN + out0: 96 blocks = (b, p-chunk); W1/W2 amortized, coalesced out ----
__global__ __launch_bounds__(256) void ffnker(const float* __restrict__ W1,
                                              const float* __restrict__ b1,
                                              const float* __restrict__ W2,
                                              const float* __restrict__ b2,
                                              const float* __restrict__ ws,
                                              float* __restrict__ out) {
    __shared__ float pl[64 * 16];      // pooled for this b
    __shared__ float hS[64 * 129];     // h[d][j], pad 129 (2-way free)
    int t  = threadIdx.x;
    int b  = blockIdx.x / 3;
    int pc = blockIdx.x % 3;           // 32-wide p chunk

    // stage pooled[b]: 1024 consecutive floats
    {
        const float* src = ws + WS_PL + b * 1024;
        for (int i = t; i < 1024; i += 256) pl[i] = src[i];
    }
    __syncthreads();

    // ---- h[d][j] = leaky(pooled[d] . W1[:,j] + b1[j]) ----
    {
        int j = t & 127, dg = t >> 7;  // dg in {0,1}
        float w1r[16];
        #pragma unroll
        for (int l = 0; l < 16; l++) w1r[l] = W1[l * H_ + j];
        float bj = b1[j];
        for (int dd = 0; dd < 32; dd++) {
            int d = dg * 32 + dd;
            const float* pd = &pl[d * 16];
            float a = bj;
            #pragma unroll
            for (int l = 0; l < 16; l++) a += pd[l] * w1r[l];
            hS[d * 129 + j] = a > 0.f ? a : 0.2f * a;
        }
    }
    __syncthreads();

    // ---- out0[b, p, d] = h[d] . W2[:,p] + b2[p]; thread = (d, 8 p's) ----
    {
        int d  = t & 63, pg = t >> 6;  // pg in {0..3}
        int p0 = pc * 32 + pg * 8;
        float acc[8];
        #pragma unroll
        for (int k = 0; k < 8; k++) acc[k] = b2[p0 + k];
        const float* hd = &hS[d * 129];
        for (int j = 0; j < 128; j++) {
            float hj = hd[j];                 // 2-way bank alias: free
            const float* w2 = W2 + j * P_ + p0;
            #pragma unroll
            for (int k = 0; k < 8; k++) acc[k] += hj * w2[k];
        }
        float* op = out + b * (P_ * D_) + d;  // out0[b][p][d]
        #pragma unroll
        for (int k = 0; k < 8; k++) op[(p0 + k) * D_] = acc[k];
    }
}

extern "C" void kernel_launch(void* const* d_in, const int* in_sizes, int n_in,
                              void* d_out, int out_size, void* d_ws, size_t ws_size,
                              hipStream_t stream) {
    const float* x     = (const float*)d_in[0];
    const float* W_enc = (const float*)d_in[1];
    const float* b_enc = (const float*)d_in[2];
    const float* W1    = (const float*)d_in[3];
    const float* b1    = (const float*)d_in[4];
    const float* W2    = (const float*)d_in[5];
    const float* b2    = (const float*)d_in[6];
    const float* pos   = (const float*)d_in[7];
    float* ws  = (float*)d_ws;
    float* out = (float*)d_out;

    hipLaunchKernelGGL(preK,     dim3(16),    dim3(256), 0, stream, pos, ws);
    hipLaunchKernelGGL(pre2b,    dim3(255),   dim3(128), 0, stream, W_enc, b_enc, pos, ws);
    hipLaunchKernelGGL(mainker2, dim3(PAIRS), dim3(256), 0, stream, x, ws, out);
    hipLaunchKernelGGL(ffnker,   dim3(96),    dim3(256), 0, stream, W1, b1, W2, b2, ws, out);
}

// Round 7
// 131.860 us; speedup vs baseline: 1.1504x; 1.0037x over previous
//
#include <hip/hip_runtime.h>
#include <hip/hip_bf16.h>

#define B_ 32
#define D_ 64
#define N_ 254
#define L_ 16
#define H_ 128
#define P_ 96
#define PAIRS (B_*D_)    // 2048
#define XPAIR (N_*L_)    // 4064 floats per (b,d) pair
#define OUT0  (B_*P_*D_) // 196608 floats (output 0)

// ws layout (floats):
#define WS_M    128      // M[256] = W_enc W_enc^T
#define WS_VK   384      // vK[16] = W_enc @ K
#define WS_BW   400      // bW[16] = W_enc @ b_enc
#define WS_BK   416      // bK     = b_enc . K
#define WS_G    432      // G[254*16] = pos @ W_enc^T
#define WS_PK   4496     // pK[254]   = pos @ K
#define WS_PL   8192     // pooled[2048][16]

// ---- fused precompute: blocks 0..253 -> G[n],pK[n]; block 254 -> M,vK,bW,bK ----
// Each block redundantly computes K = 254*b_enc + colsum(pos) (L2/L3-hot).
__global__ __launch_bounds__(128) void preAll(const float* __restrict__ W_enc,
                                              const float* __restrict__ b_enc,
                                              const float* __restrict__ pos,
                                              float* __restrict__ ws) {
    __shared__ float Ks[128], bL[128], pLDS[128], red[128], red2[128];
    __shared__ float WL[2048];
    int t = threadIdx.x;                  // 128 threads
    int n = blockIdx.x;                   // 0..254

    // K[t] = 254*b_enc[t] + sum_r pos[r][t]  (coalesced, 4 accumulators)
    {
        const float* pc0 = pos + t;
        float a0 = 0.f, a1 = 0.f, a2 = 0.f, a3 = 0.f;
        for (int r = 0; r < 252; r += 4) {
            a0 += pc0[(r + 0) * H_];
            a1 += pc0[(r + 1) * H_];
            a2 += pc0[(r + 2) * H_];
            a3 += pc0[(r + 3) * H_];
        }
        a0 += pc0[252 * H_];
        a1 += pc0[253 * H_];
        float b = b_enc[t];
        Ks[t] = 254.f * b + (a0 + a1) + (a2 + a3);
        bL[t] = b;
    }

    if (n < N_) {
        pLDS[t] = pos[n * H_ + t];
        __syncthreads();
        {
            int l = t >> 3, c = t & 7;
            const float* w = W_enc + l * H_ + c * 16;
            const float* p = pLDS + c * 16;
            float s = 0.f;
            #pragma unroll
            for (int i = 0; i < 16; i++) s += p[i] * w[i];
            red[t] = s;
            red2[t] = pLDS[t] * Ks[t];
        }
        __syncthreads();
        if (t < 16) {                     // G[n][t]
            float s = 0.f;
            #pragma unroll
            for (int c = 0; c < 8; c++) s += red[t * 8 + c];
            ws[WS_G + n * 16 + t] = s;
        }
        if (t >= 64) {                    // pK[n] (wave 1)
            int lane = t - 64;
            float s = red2[lane] + red2[lane + 64];
            for (int off = 32; off; off >>= 1) s += __shfl_down(s, off);
            if (lane == 0) ws[WS_PK + n] = s;
        }
    } else {
        // block 254: stage W_enc into LDS, compute M, vK, bW, bK
        for (int i = t; i < 512; i += 128) {
            float4 v = ((const float4*)W_enc)[i];
            float* p = &WL[i * 4];
            p[0] = v.x; p[1] = v.y; p[2] = v.z; p[3] = v.w;
        }
        __syncthreads();
        #pragma unroll
        for (int e0 = 0; e0 < 2; e0++) {
            int e = e0 * 128 + t;
            int l1 = e >> 4, l2 = e & 15;
            float s = 0.f;
            for (int h = 0; h < H_; h++) s += WL[l1 * H_ + h] * WL[l2 * H_ + h];
            ws[WS_M + e] = s;
        }
        if (t < 16) {
            float s1 = 0.f, s2 = 0.f;
            for (int h = 0; h < H_; h++) {
                float w = WL[t * H_ + h];
                s1 += w * Ks[h];
                s2 += w * bL[h];
            }
            ws[WS_VK + t] = s1;
            ws[WS_BW + t] = s2;
        }
        if (t == 16) {
            float s = 0.f;
            for (int h = 0; h < H_; h++) s += bL[h] * Ks[h];
            ws[WS_BK] = s;
        }
    }
}

// ---- main pass: block per bd; copy + score + pool ----
__global__ __launch_bounds__(256) void mainker2(const float* __restrict__ x,
                                                float* __restrict__ ws,
                                                float* __restrict__ out) {
    __shared__ float xf[N_ * 17];   // stride-17 padded
    __shared__ float red[256];
    __shared__ float scoreS[N_];
    __shared__ float xsS[16], vS[16];
    __shared__ float s0S, denomS;

    int t  = threadIdx.x;
    int bd = blockIdx.x;

    // ---- coalesced load x -> LDS, mirror copy -> out1 ----
    const float4* xv = (const float4*)(x + (size_t)bd * XPAIR);
    float4*       cv = (float4*)(out + OUT0) + (size_t)bd * (XPAIR / 4);
    for (int i = t; i < XPAIR / 4; i += 256) {
        float4 v = xv[i];
        cv[i] = v;
        int idx = i * 4, n = idx >> 4, l = idx & 15;   // l in {0,4,8,12}
        float* p = &xf[n * 17 + l];
        p[0] = v.x; p[1] = v.y; p[2] = v.z; p[3] = v.w;
    }
    __syncthreads();

    // ---- xs[l] = sum_n x[n,l] ----
    {
        int l = t & 15, g = t >> 4;
        float s = 0.f;
        for (int n = g; n < N_; n += 16) s += xf[n * 17 + l];
        red[t] = s;
    }
    __syncthreads();
    if (t < 16) {
        float s = 0.f;
        for (int g = 0; g < 16; g++) s += red[g * 16 + t];
        xsS[t] = s;
    }
    __syncthreads();

    // ---- v = vK + M^T xs; s0 = bK + xs.bW ----
    if (t < 16) {
        float s = ws[WS_VK + t];
        for (int l2 = 0; l2 < 16; l2++) s += xsS[l2] * ws[WS_M + l2 * 16 + t];
        vS[t] = s;
    } else if (t == 16) {
        float s = ws[WS_BK];
        for (int l = 0; l < 16; l++) s += xsS[l] * ws[WS_BW + l];
        s0S = s;
    }
    __syncthreads();

    // ---- score[n] = s0 + pK[n] + x[n].v + xs.G[n] ----
    if (t < N_) {
        const float4* Gn = (const float4*)(ws + WS_G + t * 16);
        float4 g0 = Gn[0], g1 = Gn[1], g2 = Gn[2], g3 = Gn[3];
        const float* xr = &xf[t * 17];
        float s = s0S + ws[WS_PK + t];
        s += xr[0]*vS[0] + xr[1]*vS[1] + xr[2]*vS[2] + xr[3]*vS[3]
           + xr[4]*vS[4] + xr[5]*vS[5] + xr[6]*vS[6] + xr[7]*vS[7]
           + xr[8]*vS[8] + xr[9]*vS[9] + xr[10]*vS[10] + xr[11]*vS[11]
           + xr[12]*vS[12] + xr[13]*vS[13] + xr[14]*vS[14] + xr[15]*vS[15];
        s += g0.x*xsS[0] + g0.y*xsS[1] + g0.z*xsS[2] + g0.w*xsS[3]
           + g1.x*xsS[4] + g1.y*xsS[5] + g1.z*xsS[6] + g1.w*xsS[7]
           + g2.x*xsS[8] + g2.y*xsS[9] + g2.z*xsS[10] + g2.w*xsS[11]
           + g3.x*xsS[12] + g3.y*xsS[13] + g3.z*xsS[14] + g3.w*xsS[15];
        scoreS[t] = s;
    }
    __syncthreads();

    // ---- denom = sum |score| ----
    if (t < 64) {
        float s = 0.f;
        for (int n = t; n < N_; n += 64) s += fabsf(scoreS[n]);
        for (int off = 32; off; off >>= 1) s += __shfl_down(s, off);
        if (t == 0) denomS = s;
    }
    __syncthreads();

    // ---- pooled[l] = (sum_n x[n,l]*score[n]) / denom -> ws ----
    {
        int l = t & 15, g = t >> 4;
        float s = 0.f;
        for (int n = g; n < N_; n += 16) s += xf[n * 17 + l] * scoreS[n];
        red[t] = s;
    }
    __syncthreads();
    if (t < 16) {
        float s = 0.f;
        for (int g = 0; g < 16; g++) s += red[g * 16 + t];
        ws[WS_PL + bd * 16 + t] = s / denomS;
    }
}

// ---- FFN + out0: 96 blocks = (b, p-chunk) ----
__global__ __launch_bounds__(256) void ffnker(const float* __restrict__ W1,
                                              const float* __restrict__ b1,
                                              const float* __restrict__ W2,
                                              const float* __restrict__ b2,
                                              const float* __restrict__ ws,
                                              float* __restrict__ out) {
    __shared__ float pl[64 * 16];
    __shared__ float hS[64 * 129];
    int t  = threadIdx.x;
    int b  = blockIdx.x / 3;
    int pc = blockIdx.x % 3;

    {
        const float* src = ws + WS_PL + b * 1024;
        for (int i = t; i < 1024; i += 256) pl[i] = src[i];
    }
    __syncthreads();

    {
        int j = t & 127, dg = t >> 7;
        float w1r[16];
        #pragma unroll
        for (int l = 0; l < 16; l++) w1r[l] = W1[l * H_ + j];
        float bj = b1[j];
        for (int dd = 0; dd < 32; dd++) {
            int d = dg * 32 + dd;
            const float* pd = &pl[d * 16];
            float a = bj;
            #pragma unroll
            for (int l = 0; l < 16; l++) a += pd[l] * w1r[l];
            hS[d * 129 + j] = a > 0.f ? a : 0.2f * a;
        }
    }
    __syncthreads();

    {
        int d  = t & 63, pg = t >> 6;
        int p0 = pc * 32 + pg * 8;
        float acc[8];
        #pragma unroll
        for (int k = 0; k < 8; k++) acc[k] = b2[p0 + k];
        const float* hd = &hS[d * 129];
        for (int j = 0; j < 128; j++) {
            float hj = hd[j];
            const float* w2 = W2 + j * P_ + p0;
            #pragma unroll
            for (int k = 0; k < 8; k++) acc[k] += hj * w2[k];
        }
        float* op = out + b * (P_ * D_) + d;
        #pragma unroll
        for (int k = 0; k < 8; k++) op[(p0 + k) * D_] = acc[k];
    }
}

extern "C" void kernel_launch(void* const* d_in, const int* in_sizes, int n_in,
                              void* d_out, int out_size, void* d_ws, size_t ws_size,
                              hipStream_t stream) {
    const float* x     = (const float*)d_in[0];
    const float* W_enc = (const float*)d_in[1];
    const float* b_enc = (const float*)d_in[2];
    const float* W1    = (const float*)d_in[3];
    const float* b1    = (const float*)d_in[4];
    const float* W2    = (const float*)d_in[5];
    const float* b2    = (const float*)d_in[6];
    const float* pos   = (const float*)d_in[7];
    float* ws  = (float*)d_ws;
    float* out = (float*)d_out;

    hipLaunchKernelGGL(preAll,   dim3(255),   dim3(128), 0, stream, W_enc, b_enc, pos, ws);
    hipLaunchKernelGGL(mainker2, dim3(PAIRS), dim3(256), 0, stream, x, ws, out);
    hipLaunchKernelGGL(ffnker,   dim3(96),    dim3(256), 0, stream, W1, b1, W2, b2, ws, out);
}

// Round 8
// 121.558 us; speedup vs baseline: 1.2479x; 1.0848x over previous
//
#include <hip/hip_runtime.h>
#include <hip/hip_bf16.h>

#define B_ 32
#define D_ 64
#define N_ 254
#define L_ 16
#define H_ 128
#define P_ 96
#define PAIRS (B_*D_)    // 2048
#define XPAIR (N_*L_)    // 4064 floats per (b,d) pair
#define OUT0  (B_*P_*D_) // 196608 floats (output 0)

// ws layout (floats):
#define WS_M    128      // M[256] = W_enc W_enc^T
#define WS_VK   384      // vK[16] = W_enc @ K
#define WS_BW   400      // bW[16] = W_enc @ b_enc
#define WS_BK   416      // bK     = b_enc . K
#define WS_G    432      // G[254*16] = pos @ W_enc^T
#define WS_PK   4496     // pK[254]   = pos @ K

// ---- fused precompute: blocks 0..253 -> G[n],pK[n]; block 254 -> M,vK,bW,bK ----
__global__ __launch_bounds__(128) void preAll(const float* __restrict__ W_enc,
                                              const float* __restrict__ b_enc,
                                              const float* __restrict__ pos,
                                              float* __restrict__ ws) {
    __shared__ float Ks[128], bL[128], pLDS[128], red[128], red2[128];
    __shared__ float WL[2048];
    int t = threadIdx.x;                  // 128 threads
    int n = blockIdx.x;                   // 0..254

    // K[t] = 254*b_enc[t] + colsum(pos)[t]  (coalesced, 4 accumulators, L2/L3-hot)
    {
        const float* pc0 = pos + t;
        float a0 = 0.f, a1 = 0.f, a2 = 0.f, a3 = 0.f;
        for (int r = 0; r < 252; r += 4) {
            a0 += pc0[(r + 0) * H_];
            a1 += pc0[(r + 1) * H_];
            a2 += pc0[(r + 2) * H_];
            a3 += pc0[(r + 3) * H_];
        }
        a0 += pc0[252 * H_];
        a1 += pc0[253 * H_];
        float b = b_enc[t];
        Ks[t] = 254.f * b + (a0 + a1) + (a2 + a3);
        bL[t] = b;
    }

    if (n < N_) {
        pLDS[t] = pos[n * H_ + t];
        __syncthreads();
        {
            int l = t >> 3, c = t & 7;
            const float* w = W_enc + l * H_ + c * 16;
            const float* p = pLDS + c * 16;
            float s = 0.f;
            #pragma unroll
            for (int i = 0; i < 16; i++) s += p[i] * w[i];
            red[t] = s;
            red2[t] = pLDS[t] * Ks[t];
        }
        __syncthreads();
        if (t < 16) {                     // G[n][t]
            float s = 0.f;
            #pragma unroll
            for (int c = 0; c < 8; c++) s += red[t * 8 + c];
            ws[WS_G + n * 16 + t] = s;
        }
        if (t >= 64) {                    // pK[n] (wave 1)
            int lane = t - 64;
            float s = red2[lane] + red2[lane + 64];
            for (int off = 32; off; off >>= 1) s += __shfl_down(s, off);
            if (lane == 0) ws[WS_PK + n] = s;
        }
    } else {
        // block 254: stage W_enc into LDS, compute M, vK, bW, bK
        for (int i = t; i < 512; i += 128) {
            float4 v = ((const float4*)W_enc)[i];
            float* p = &WL[i * 4];
            p[0] = v.x; p[1] = v.y; p[2] = v.z; p[3] = v.w;
        }
        __syncthreads();
        #pragma unroll
        for (int e0 = 0; e0 < 2; e0++) {
            int e = e0 * 128 + t;
            int l1 = e >> 4, l2 = e & 15;
            float s = 0.f;
            for (int h = 0; h < H_; h++) s += WL[l1 * H_ + h] * WL[l2 * H_ + h];
            ws[WS_M + e] = s;
        }
        if (t < 16) {
            float s1 = 0.f, s2 = 0.f;
            for (int h = 0; h < H_; h++) {
                float w = WL[t * H_ + h];
                s1 += w * Ks[h];
                s2 += w * bL[h];
            }
            ws[WS_VK + t] = s1;
            ws[WS_BW + t] = s2;
        }
        if (t == 16) {
            float s = 0.f;
            for (int h = 0; h < H_; h++) s += bL[h] * Ks[h];
            ws[WS_BK] = s;
        }
    }
}

// ---- main: block per bd; copy + score + pool + FFN fused (FFN overlaps
// other blocks' memory phases — separate FFN kernel was a 13us tail, R6/R7) ----
__global__ __launch_bounds__(256) void mainker3(const float* __restrict__ x,
                                                const float* __restrict__ W1,
                                                const float* __restrict__ b1,
                                                const float* __restrict__ W2,
                                                const float* __restrict__ b2,
                                                const float* __restrict__ ws,
                                                float* __restrict__ out) {
    __shared__ float xf[N_ * 17];   // stride-17 padded
    __shared__ float red[256];
    __shared__ float scoreS[N_];
    __shared__ float xsS[16], vS[16], pooledS[16], hS[128];
    __shared__ float s0S, denomS;

    int t  = threadIdx.x;
    int bd = blockIdx.x;

    // ---- coalesced load x -> LDS, mirror copy -> out1 (dominant HBM traffic) ----
    const float4* xv = (const float4*)(x + (size_t)bd * XPAIR);
    float4*       cv = (float4*)(out + OUT0) + (size_t)bd * (XPAIR / 4);
    for (int i = t; i < XPAIR / 4; i += 256) {
        float4 v = xv[i];
        cv[i] = v;
        int idx = i * 4, n = idx >> 4, l = idx & 15;   // l in {0,4,8,12}
        float* p = &xf[n * 17 + l];
        p[0] = v.x; p[1] = v.y; p[2] = v.z; p[3] = v.w;
    }
    __syncthreads();

    // ---- xs[l] = sum_n x[n,l] ----
    {
        int l = t & 15, g = t >> 4;
        float s = 0.f;
        for (int n = g; n < N_; n += 16) s += xf[n * 17 + l];
        red[t] = s;
    }
    __syncthreads();
    if (t < 16) {
        float s = 0.f;
        for (int g = 0; g < 16; g++) s += red[g * 16 + t];
        xsS[t] = s;
    }
    __syncthreads();

    // ---- v = vK + M^T xs; s0 = bK + xs.bW  (tables L1/L2-hot) ----
    if (t < 16) {
        float s = ws[WS_VK + t];
        for (int l2 = 0; l2 < 16; l2++) s += xsS[l2] * ws[WS_M + l2 * 16 + t];
        vS[t] = s;
    } else if (t == 16) {
        float s = ws[WS_BK];
        for (int l = 0; l < 16; l++) s += xsS[l] * ws[WS_BW + l];
        s0S = s;
    }
    __syncthreads();

    // ---- score[n] = s0 + pK[n] + x[n].v + xs.G[n] ----
    if (t < N_) {
        const float4* Gn = (const float4*)(ws + WS_G + t * 16);
        float4 g0 = Gn[0], g1 = Gn[1], g2 = Gn[2], g3 = Gn[3];
        const float* xr = &xf[t * 17];
        float s = s0S + ws[WS_PK + t];
        s += xr[0]*vS[0] + xr[1]*vS[1] + xr[2]*vS[2] + xr[3]*vS[3]
           + xr[4]*vS[4] + xr[5]*vS[5] + xr[6]*vS[6] + xr[7]*vS[7]
           + xr[8]*vS[8] + xr[9]*vS[9] + xr[10]*vS[10] + xr[11]*vS[11]
           + xr[12]*vS[12] + xr[13]*vS[13] + xr[14]*vS[14] + xr[15]*vS[15];
        s += g0.x*xsS[0] + g0.y*xsS[1] + g0.z*xsS[2] + g0.w*xsS[3]
           + g1.x*xsS[4] + g1.y*xsS[5] + g1.z*xsS[6] + g1.w*xsS[7]
           + g2.x*xsS[8] + g2.y*xsS[9] + g2.z*xsS[10] + g2.w*xsS[11]
           + g3.x*xsS[12] + g3.y*xsS[13] + g3.z*xsS[14] + g3.w*xsS[15];
        scoreS[t] = s;
    }
    __syncthreads();

    // ---- denom = sum |score| ----
    if (t < 64) {
        float s = 0.f;
        for (int n = t; n < N_; n += 64) s += fabsf(scoreS[n]);
        for (int off = 32; off; off >>= 1) s += __shfl_down(s, off);
        if (t == 0) denomS = s;
    }
    __syncthreads();

    // ---- pooled[l] = (sum_n x[n,l]*score[n]) / denom ----
    {
        int l = t & 15, g = t >> 4;
        float s = 0.f;
        for (int n = g; n < N_; n += 16) s += xf[n * 17 + l] * scoreS[n];
        red[t] = s;
    }
    __syncthreads();
    if (t < 16) {
        float s = 0.f;
        for (int g = 0; g < 16; g++) s += red[g * 16 + t];
        pooledS[t] = s / denomS;
    }
    __syncthreads();

    // ---- h = leaky_relu(pooled @ W1 + b1, 0.2) ----
    if (t < 128) {
        float s = b1[t];
        #pragma unroll
        for (int l = 0; l < 16; l++) s += pooledS[l] * W1[l * H_ + t];
        hS[t] = s > 0.f ? s : 0.2f * s;
    }
    __syncthreads();

    // ---- out0[b,p,d] = h @ W2 + b2 : 192 threads, split-j halves ----
    if (t < 192) {
        int p = t % 96, half = t / 96;
        const float* hh = &hS[half * 64];
        const float* w2 = W2 + half * 64 * P_ + p;
        float acc = 0.f;
        #pragma unroll 8
        for (int j = 0; j < 64; j++) acc += hh[j] * w2[j * P_];
        red[t] = acc;
    }
    __syncthreads();
    if (t < 96) {
        int b = bd >> 6, d = bd & 63;
        out[b * (P_ * D_) + t * D_ + d] = red[t] + red[t + 96] + b2[t];
    }
}

extern "C" void kernel_launch(void* const* d_in, const int* in_sizes, int n_in,
                              void* d_out, int out_size, void* d_ws, size_t ws_size,
                              hipStream_t stream) {
    const float* x     = (const float*)d_in[0];
    const float* W_enc = (const float*)d_in[1];
    const float* b_enc = (const float*)d_in[2];
    const float* W1    = (const float*)d_in[3];
    const float* b1    = (const float*)d_in[4];
    const float* W2    = (const float*)d_in[5];
    const float* b2    = (const float*)d_in[6];
    const float* pos   = (const float*)d_in[7];
    float* ws  = (float*)d_ws;
    float* out = (float*)d_out;

    hipLaunchKernelGGL(preAll,   dim3(255),   dim3(128), 0, stream, W_enc, b_enc, pos, ws);
    hipLaunchKernelGGL(mainker3, dim3(PAIRS), dim3(256), 0, stream, x, W1, b1, W2, b2, ws, out);
}